// Round 10
// baseline (126.858 us; speedup 1.0000x reference)
//
#include <hip/hip_runtime.h>
#include <hip/hip_fp16.h>
#include <math.h>

#define PH 7
#define PW 7
#define B_ 4
#define C_ 256
#define H_ 50
#define W_ 50
#define R_ 256
#define S_ (H_ * W_)       // 2500
#define NCELL (PH * PW)    // 49
#define MAXW 9             // max window width/height per cell
#define OUTR (C_ * NCELL)  // 12544 floats per roi

// ---------- kernel 1: features (B,C,H,W) fp32 -> (B,H,W,C) fp16 ----------
// 64ch x 32s LDS tile, convert on read, pack 2 halves per 4-B store.
__global__ void transpose_pack_half(const float* __restrict__ in,
                                    __half* __restrict__ out) {
    __shared__ unsigned short tile[64][33];
    const int b  = blockIdx.z;
    const int s0 = blockIdx.x * 32;
    const int c0 = blockIdx.y * 64;
    const float* inb  = in  + (size_t)b * C_ * S_;
    __half*      outb = out + (size_t)b * S_ * C_;
    const int tx = threadIdx.x;   // 0..31
    const int ty = threadIdx.y;   // 0..7

    #pragma unroll
    for (int i = ty; i < 64; i += 8) {
        const int s = s0 + tx;
        if (s < S_) {
            __half h = __float2half(inb[(size_t)(c0 + i) * S_ + s]);
            tile[i][tx] = *(unsigned short*)&h;
        }
    }
    __syncthreads();
    #pragma unroll
    for (int i = ty; i < 32; i += 8) {
        const int s = s0 + i;
        if (s < S_) {
            const unsigned int v = (unsigned int)tile[2 * tx][i]
                                 | ((unsigned int)tile[2 * tx + 1][i] << 16);
            *(unsigned int*)&outb[(size_t)s * C_ + c0 + 2 * tx] = v;  // even addr
        }
    }
}

// ROCm 7.2 hip_fp16.h has no __hmax2 — build it from scalar __hmax.
// Compiler pairs these into v_pk_max_f16; worst case 2x v_max_f16 (noise).
__device__ __forceinline__ __half2 hmax2(__half2 a, __half2 b) {
    return __halves2half2(__hmax(__low2half(a),  __low2half(b)),
                          __hmax(__high2half(a), __high2half(b)));
}

// ---------- kernel 2: fused pool (fp16 in, fp32 out) ----------
// One block (1024 thr = 16 waves) per roi; wave owns cells {w, w+16, w+32}.
// Lane owns 4 channels: one uint2 (4 halves) per point, 512 B/wave coalesced.
// 3-row x kw guarded batches (wave-uniform branches): <=27 loads in flight.
// max commutes with monotone fp16 rounding -> single-rounding error ~0.003
// << 0.0994 threshold. Results staged in flat c-major LDS image of out[r],
// flushed as one contiguous 50 KB coalesced copy.
__global__ void __launch_bounds__(1024)
roi_pool_h(const __half* __restrict__ fth, const int* __restrict__ rois,
           float* __restrict__ out) {
    __shared__ float obuf[OUTR];   // 50176 B

    const int r    = blockIdx.x;
    const int t    = threadIdx.x;
    const int wave = t >> 6;       // 0..15
    const int lane = t & 63;

    const int* roi = rois + r * 5;
    const int b  = roi[0];
    const int x1 = roi[1] >> 4;    // floor(v/16), v >= 0
    const int y1 = roi[2] >> 4;
    const int x2 = roi[3] >> 4;
    const int y2 = roi[4] >> 4;
    const int h = y2 - y1 + 1;
    const int w = x2 - x1 + 1;

    const __half* fb = fth + (size_t)b * S_ * C_ + 4 * lane;
    const __half2 ninf2 = __half2half2(__float2half(-INFINITY));

    for (int cell = wave; cell < NCELL; cell += 16) {
        const int ph = cell / PW;
        const int pw = cell - ph * PW;
        const int sh = y1 + (ph * h) / PH;
        const int eh = y1 + ((ph + 1) * h + PH - 1) / PH;
        const int sw = x1 + (pw * w) / PW;
        const int ew = x1 + ((pw + 1) * w + PW - 1) / PW;
        const int kw = ew - sw;    // 1..9, wave-uniform

        __half2 m0 = ninf2, m1 = ninf2;
        for (int y = sh; y < eh; y += 3) {
            const int nr = eh - y;  // remaining rows; process min(3, nr)
            uint2 v[3][MAXW];
            #pragma unroll
            for (int j = 0; j < 3; ++j) {
                if (j < nr) {       // wave-uniform
                    const __half* p = fb + (size_t)((y + j) * W_ + sw) * C_;
                    #pragma unroll
                    for (int k = 0; k < MAXW; ++k) {
                        if (k < kw) v[j][k] = *(const uint2*)(p + (size_t)k * C_);
                    }
                }
            }
            #pragma unroll
            for (int j = 0; j < 3; ++j) {
                if (j < nr) {
                    #pragma unroll
                    for (int k = 0; k < MAXW; ++k) {
                        if (k < kw) {
                            m0 = hmax2(m0, *(const __half2*)&v[j][k].x);
                            m1 = hmax2(m1, *(const __half2*)&v[j][k].y);
                        }
                    }
                }
            }
        }

        const float2 f0 = __half22float2(m0);
        const float2 f1 = __half22float2(m1);
        const int c = 4 * lane;
        obuf[(c + 0) * NCELL + cell] = f0.x;
        obuf[(c + 1) * NCELL + cell] = f0.y;
        obuf[(c + 2) * NCELL + cell] = f1.x;
        obuf[(c + 3) * NCELL + cell] = f1.y;
    }

    __syncthreads();

    // contiguous 50 KB flush: LDS float4 (conflict-free) -> global float4
    const float4* src4 = (const float4*)obuf;
    float4* dst4 = (float4*)(out + (size_t)r * OUTR);
    #pragma unroll
    for (int fi = t; fi < OUTR / 4; fi += 1024) {
        dst4[fi] = src4[fi];
    }
}

extern "C" void kernel_launch(void* const* d_in, const int* in_sizes, int n_in,
                              void* d_out, int out_size, void* d_ws, size_t ws_size,
                              hipStream_t stream) {
    const float* features = (const float*)d_in[0];
    const int*   rois     = (const int*)d_in[1];
    float*       out      = (float*)d_out;

    __half* fth = (__half*)d_ws;   // 5.12 MB of scratch
    dim3 tgrid((S_ + 31) / 32, C_ / 64, B_);
    transpose_pack_half<<<tgrid, dim3(32, 8), 0, stream>>>(features, fth);
    roi_pool_h<<<R_, 1024, 0, stream>>>(fth, rois, out);
}

// Round 11
// 112.588 us; speedup vs baseline: 1.1267x; 1.1267x over previous
//
#include <hip/hip_runtime.h>
#include <hip/hip_fp16.h>
#include <math.h>

#define PH 7
#define PW 7
#define B_ 4
#define C_ 256
#define H_ 50
#define W_ 50
#define R_ 256
#define S_ (H_ * W_)       // 2500
#define NCELL (PH * PW)    // 49
#define OUTR (C_ * NCELL)  // 12544 floats per roi

// ---------- kernel 1: features (B,C,H,W) fp32 -> (B,H,W,C) fp16 ----------
__global__ void transpose_pack_half(const float* __restrict__ in,
                                    __half* __restrict__ out) {
    __shared__ unsigned short tile[64][33];
    const int b  = blockIdx.z;
    const int s0 = blockIdx.x * 32;
    const int c0 = blockIdx.y * 64;
    const float* inb  = in  + (size_t)b * C_ * S_;
    __half*      outb = out + (size_t)b * S_ * C_;
    const int tx = threadIdx.x;   // 0..31
    const int ty = threadIdx.y;   // 0..7

    #pragma unroll
    for (int i = ty; i < 64; i += 8) {
        const int s = s0 + tx;
        if (s < S_) {
            __half h = __float2half(inb[(size_t)(c0 + i) * S_ + s]);
            tile[i][tx] = *(unsigned short*)&h;
        }
    }
    __syncthreads();
    #pragma unroll
    for (int i = ty; i < 32; i += 8) {
        const int s = s0 + i;
        if (s < S_) {
            const unsigned int v = (unsigned int)tile[2 * tx][i]
                                 | ((unsigned int)tile[2 * tx + 1][i] << 16);
            *(unsigned int*)&outb[(size_t)s * C_ + c0 + 2 * tx] = v;
        }
    }
}

// ROCm 7.2 hip_fp16.h has no __hmax2 — build from scalar __hmax.
__device__ __forceinline__ __half2 hmax2(__half2 a, __half2 b) {
    return __halves2half2(__hmax(__low2half(a),  __low2half(b)),
                          __hmax(__high2half(a), __high2half(b)));
}

// Pool one cell with FORCED ILP: per round, 2 rows x KW unconditional
// uint2 loads (x clamped to min(k,kw-1) — duplicates are max-idempotent).
// NO branches between loads -> compiler must hold 2*KW uint2 in VGPRs
// (verifiable: VGPR_Count >= ~56). R10 post-mortem: guarded loads collapsed
// to VGPR=36 = serialized chain = 62 us.
template <int KW>
__device__ __forceinline__ void pool_cell(const __half* __restrict__ fb,
                                          int sh, int eh, int sw, int kw,
                                          __half2& m0, __half2& m1) {
    for (int y = sh; y < eh; y += 2) {
        const int yb = (y + 1 < eh) ? (y + 1) : y;   // dup row, max-safe
        const __half* p0 = fb + (size_t)(y  * W_ + sw) * C_;
        const __half* p1 = fb + (size_t)(yb * W_ + sw) * C_;
        uint2 v0[KW], v1[KW];
        #pragma unroll
        for (int k = 0; k < KW; ++k) {
            const int xo = (k < kw) ? k : (kw - 1);  // clamp, no guard on load
            v0[k] = *(const uint2*)(p0 + (size_t)xo * C_);
            v1[k] = *(const uint2*)(p1 + (size_t)xo * C_);
        }
        #pragma unroll
        for (int k = 0; k < KW; ++k) {
            m0 = hmax2(m0, *(const __half2*)&v0[k].x);
            m1 = hmax2(m1, *(const __half2*)&v0[k].y);
            m0 = hmax2(m0, *(const __half2*)&v1[k].x);
            m1 = hmax2(m1, *(const __half2*)&v1[k].y);
        }
    }
}

// ---------- kernel 2: pool. One wave-block per (cell, roi). ----------
// 12544 blocks (49/CU queued) -> straggler-proof: worst block = one 9x9
// window (R10's 62 us was one 256-block straggler running alone).
// Store: 1 KB contiguous fp32 span per block into tmp[r][cell][c] — zero
// write amplification by construction.
__global__ void __launch_bounds__(64)
roi_pool_cell_h(const __half* __restrict__ fth, const int* __restrict__ rois,
                float* __restrict__ tmp) {
    const int bx   = blockIdx.x;
    const int cell = bx >> 8;        // 0..48
    const int r    = bx & 255;       // 0..255
    const int lane = threadIdx.x;    // 0..63

    const int* roi = rois + r * 5;
    const int b  = roi[0];
    const int x1 = roi[1] >> 4;      // floor(v/16), v >= 0
    const int y1 = roi[2] >> 4;
    const int x2 = roi[3] >> 4;
    const int y2 = roi[4] >> 4;
    const int h = y2 - y1 + 1;
    const int w = x2 - x1 + 1;

    const int ph = cell / PW;
    const int pw = cell - ph * PW;
    const int sh = y1 + (ph * h) / PH;
    const int eh = y1 + ((ph + 1) * h + PH - 1) / PH;
    const int sw = x1 + (pw * w) / PW;
    const int ew = x1 + ((pw + 1) * w + PW - 1) / PW;
    const int kw = ew - sw;          // 1..9, wave-uniform

    const __half* fb = fth + (size_t)b * S_ * C_ + 4 * lane;
    const __half2 ninf2 = __half2half2(__float2half(-INFINITY));
    __half2 m0 = ninf2, m1 = ninf2;

    if (kw <= 4) pool_cell<4>(fb, sh, eh, sw, kw, m0, m1);  // wave-uniform
    else         pool_cell<9>(fb, sh, eh, sw, kw, m0, m1);

    const float2 f0 = __half22float2(m0);
    const float2 f1 = __half22float2(m1);
    float4 o; o.x = f0.x; o.y = f0.y; o.z = f1.x; o.w = f1.y;
    *(float4*)(tmp + ((size_t)(r * NCELL + cell)) * C_ + 4 * lane) = o;
}

// ---------- kernel 3: tmp (R,49,C) -> out (R,C,49) ----------
// Padded stride 257 (257%32==1): conflict-free both phases; both global
// phases fully coalesced. (Proven in R6.)
__global__ void __launch_bounds__(256)
transpose_out(const float* __restrict__ tmp, float* __restrict__ out) {
    __shared__ float lds[NCELL * 257];
    const int r = blockIdx.x;
    const int t = threadIdx.x;
    const float* src = tmp + (size_t)r * NCELL * C_;
    float*       dst = out + (size_t)r * C_ * NCELL;

    #pragma unroll
    for (int i = t; i < NCELL * C_; i += 256) {
        const int cell = i >> 8;
        const int c    = i & 255;
        lds[cell * 257 + c] = src[i];
    }
    __syncthreads();
    #pragma unroll
    for (int f = t; f < NCELL * C_; f += 256) {
        const int c    = f / NCELL;
        const int cell = f - c * NCELL;
        dst[f] = lds[cell * 257 + c];
    }
}

extern "C" void kernel_launch(void* const* d_in, const int* in_sizes, int n_in,
                              void* d_out, int out_size, void* d_ws, size_t ws_size,
                              hipStream_t stream) {
    const float* features = (const float*)d_in[0];
    const int*   rois     = (const int*)d_in[1];
    float*       out      = (float*)d_out;

    __half* fth = (__half*)d_ws;                       // 5.12 MB
    float*  tmp = (float*)(fth + (size_t)B_ * S_ * C_); // +12.85 MB

    dim3 tgrid((S_ + 31) / 32, C_ / 64, B_);
    transpose_pack_half<<<tgrid, dim3(32, 8), 0, stream>>>(features, fth);
    roi_pool_cell_h<<<NCELL * R_, 64, 0, stream>>>(fth, rois, tmp);
    transpose_out<<<R_, 256, 0, stream>>>(tmp, out);
}